// Round 1
// baseline (420.725 us; speedup 1.0000x reference)
//
#include <hip/hip_runtime.h>

constexpr float SLOPE = 0.1f;
constexpr float BN_EPS = 1e-5f;

// ---------- K1: degree counting ----------
__global__ void k_count(const int* __restrict__ row, const int* __restrict__ col, int E,
                        int* __restrict__ cntOut, int* __restrict__ cntIn) {
    int i = blockIdx.x * blockDim.x + threadIdx.x;
    if (i < E) {
        atomicAdd(&cntOut[row[i]], 1);
        atomicAdd(&cntIn[col[i]], 1);
    }
}

// ---------- K2: single-block exclusive scan of cntIn -> csr_off[0..N] ----------
__global__ void k_scan(const int* __restrict__ cntIn, int* __restrict__ csr_off, int N) {
    __shared__ int part[1024];
    int t = threadIdx.x;
    int chunk = (N + 1023) >> 10;
    int b = t * chunk;
    int e = min(b + chunk, N);
    int s = 0;
    for (int i = b; i < e; ++i) s += cntIn[i];
    part[t] = s;
    __syncthreads();
    for (int d = 1; d < 1024; d <<= 1) {
        int v = (t >= d) ? part[t - d] : 0;
        __syncthreads();
        part[t] += v;
        __syncthreads();
    }
    int run = part[t] - s;  // exclusive prefix for this thread's chunk
    for (int i = b; i < e; ++i) { csr_off[i] = run; run += cntIn[i]; }
    if (t == 1023) csr_off[N] = part[1023];
}

// ---------- K3: per-node deg/dis + deg2 init (self-loop contributions) ----------
__global__ void k_nodeinit(const int* __restrict__ cntOut, float* __restrict__ dis,
                           float* __restrict__ deg2, int N) {
    int i = blockIdx.x * blockDim.x + threadIdx.x;
    if (i < N) {
        float dg = (float)(cntOut[i] + 1);   // deg = outdeg + self-loop
        float ds = rsqrtf(dg);
        dis[i] = ds;
        // deg2[i] = 2.0 (fill self-loop) + dis[i]^2 (ei1 self-loop w1)
        deg2[i] = 2.0f + ds * ds;
    }
}

// ---------- K4: per-edge w1, deg2 scatter, CSR fill ----------
__global__ void k_edges(const int* __restrict__ row, const int* __restrict__ col, int E,
                        const float* __restrict__ dis, float* __restrict__ deg2,
                        const int* __restrict__ csr_off, int* __restrict__ csr_cur,
                        int* __restrict__ csr_row, float* __restrict__ csr_w) {
    int i = blockIdx.x * blockDim.x + threadIdx.x;
    if (i < E) {
        int r = row[i], c = col[i];
        float w1 = dis[r] * dis[c];
        atomicAdd(&deg2[c], w1);
        int pos = csr_off[c] + atomicAdd(&csr_cur[c], 1);
        csr_row[pos] = r;
        csr_w[pos] = w1;
    }
}

// ---------- K5: dis2 = rsqrt(deg2) ----------
__global__ void k_dis2(const float* __restrict__ deg2, float* __restrict__ dis2, int N) {
    int i = blockIdx.x * blockDim.x + threadIdx.x;
    if (i < N) dis2[i] = rsqrtf(deg2[i]);   // deg2 >= 2 always
}

// ---------- K6: h = x @ W^T  (fp32, LDS-tiled) ----------
// block = 256 threads, 32 rows x 128 cols per block, 4x4 per thread, K tiled by 64
__global__ __launch_bounds__(256) void k_gemm(const float* __restrict__ x,
                                              const float* __restrict__ W,
                                              float* __restrict__ h, int N) {
    __shared__ float wt[64 * 132];   // [k][d], stride 132 to break bank conflicts
    __shared__ float xs[32 * 128];   // [r][k]
    int tx = threadIdx.x;
    int row0 = blockIdx.x * 32;
    for (int idx = tx; idx < 32 * 128; idx += 256) {
        int r = idx >> 7, k = idx & 127;
        int gr = row0 + r;
        xs[idx] = (gr < N) ? x[(size_t)gr * 128 + k] : 0.0f;
    }
    int c0 = (tx & 31) * 4;
    int r0 = (tx >> 5) * 4;
    float acc[4][4] = {};
    for (int kt = 0; kt < 2; ++kt) {
        __syncthreads();
        for (int idx = tx; idx < 128 * 64; idx += 256) {
            int d = idx >> 6, k = idx & 63;
            wt[k * 132 + d] = W[d * 128 + kt * 64 + k];
        }
        __syncthreads();
        int kbase = kt * 64;
        for (int k = 0; k < 64; ++k) {
            float4 wv = *(const float4*)&wt[k * 132 + c0];
            float xv0 = xs[(r0 + 0) * 128 + kbase + k];
            float xv1 = xs[(r0 + 1) * 128 + kbase + k];
            float xv2 = xs[(r0 + 2) * 128 + kbase + k];
            float xv3 = xs[(r0 + 3) * 128 + kbase + k];
            acc[0][0] += xv0 * wv.x; acc[0][1] += xv0 * wv.y; acc[0][2] += xv0 * wv.z; acc[0][3] += xv0 * wv.w;
            acc[1][0] += xv1 * wv.x; acc[1][1] += xv1 * wv.y; acc[1][2] += xv1 * wv.z; acc[1][3] += xv1 * wv.w;
            acc[2][0] += xv2 * wv.x; acc[2][1] += xv2 * wv.y; acc[2][2] += xv2 * wv.z; acc[2][3] += xv2 * wv.w;
            acc[3][0] += xv3 * wv.x; acc[3][1] += xv3 * wv.y; acc[3][2] += xv3 * wv.z; acc[3][3] += xv3 * wv.w;
        }
    }
    for (int r = 0; r < 4; ++r) {
        int gr = row0 + r0 + r;
        if (gr < N) {
            float4 o = make_float4(acc[r][0], acc[r][1], acc[r][2], acc[r][3]);
            *(float4*)&h[(size_t)gr * 128 + c0] = o;
        }
    }
}

// ---------- K7: aggregation (one block = one destination node, no atomics) ----------
__global__ __launch_bounds__(128) void k_agg(const float* __restrict__ h,
                                             const int* __restrict__ csr_off,
                                             const int* __restrict__ csr_row,
                                             const float* __restrict__ csr_w,
                                             const float* __restrict__ dis,
                                             const float* __restrict__ dis2,
                                             const float* __restrict__ bias,
                                             float* __restrict__ agg, int N) {
    int j = blockIdx.x;
    int d = threadIdx.x;
    float d2j = dis2[j];
    float dsj = dis[j];
    float selfw = d2j * d2j * (dsj * dsj + 2.0f);   // both self-loop norms
    float acc = selfw * h[(size_t)j * 128 + d];
    int s0 = csr_off[j], s1 = csr_off[j + 1];
    for (int s = s0; s < s1; ++s) {
        int r = csr_row[s];
        float w = dis2[r] * csr_w[s] * d2j;
        acc += w * h[(size_t)r * 128 + d];
    }
    agg[(size_t)j * 128 + d] = acc + bias[d];
}

// ---------- K8: BN batch stats (sum, sumsq per feature) ----------
__global__ void k_stats(const float* __restrict__ agg, float* __restrict__ sums, int N) {
    int d = threadIdx.x & 127;
    int stream_id = blockIdx.x * 2 + (threadIdx.x >> 7);
    int nstreams = gridDim.x * 2;
    float s = 0.0f, sq = 0.0f;
    for (int i = stream_id; i < N; i += nstreams) {
        float v = agg[(size_t)i * 128 + d];
        s += v; sq += v * v;
    }
    atomicAdd(&sums[d], s);
    atomicAdd(&sums[128 + d], sq);
}

// ---------- K9: fold BN into scale/shift ----------
__global__ void k_bnfin(float* __restrict__ sums, const float* __restrict__ gamma,
                        const float* __restrict__ beta, int N) {
    int d = threadIdx.x;
    float invN = 1.0f / (float)N;
    float mu = sums[d] * invN;
    float var = sums[128 + d] * invN - mu * mu;   // biased var, like jnp.var
    float sc = gamma[d] * rsqrtf(var + BN_EPS);
    sums[256 + d] = sc;
    sums[384 + d] = beta[d] - mu * sc;
}

// ---------- K10: BN-apply + LeakyReLU + residual + LeakyReLU ----------
__global__ void k_final(const float* __restrict__ agg, const float* __restrict__ x,
                        const float* __restrict__ sums, float* __restrict__ out, int total4) {
    int idx = blockIdx.x * blockDim.x + threadIdx.x;
    if (idx >= total4) return;
    int c4 = (idx & 31) * 4;
    float4 a = *(const float4*)&agg[(size_t)idx * 4];
    float4 xv = *(const float4*)&x[(size_t)idx * 4];
    float ap[4] = {a.x, a.y, a.z, a.w};
    float xp[4] = {xv.x, xv.y, xv.z, xv.w};
    float op[4];
#pragma unroll
    for (int j = 0; j < 4; ++j) {
        int d = c4 + j;
        float bn = ap[j] * sums[256 + d] + sums[384 + d];
        float act = bn > 0.0f ? bn : SLOPE * bn;
        float v = act + xp[j];
        op[j] = v > 0.0f ? v : SLOPE * v;
    }
    float4 o = make_float4(op[0], op[1], op[2], op[3]);
    *(float4*)&out[(size_t)idx * 4] = o;
}

extern "C" void kernel_launch(void* const* d_in, const int* in_sizes, int n_in,
                              void* d_out, int out_size, void* d_ws, size_t ws_size,
                              hipStream_t stream) {
    const float* x     = (const float*)d_in[0];
    const float* W     = (const float*)d_in[1];
    const float* bias  = (const float*)d_in[2];
    const float* gamma = (const float*)d_in[3];
    const float* beta  = (const float*)d_in[4];
    const int*   ei    = (const int*)d_in[5];
    int N = in_sizes[0] / 128;
    int E = in_sizes[5] / 2;
    const int* row = ei;
    const int* col = ei + E;
    float* out = (float*)d_out;

    char* ws = (char*)d_ws;
    size_t off = 0;
    auto alloc = [&](size_t b) { size_t o = off; off = (off + b + 255) & ~(size_t)255; return o; };
    size_t o_cntOut = alloc((size_t)N * 4);
    size_t o_cntIn  = alloc((size_t)N * 4);
    size_t o_cur    = alloc((size_t)N * 4);
    size_t o_sums   = alloc(512 * 4);
    size_t zbytes   = off;                       // everything before here must be zeroed
    size_t o_coff   = alloc((size_t)(N + 1) * 4);
    size_t o_dis    = alloc((size_t)N * 4);
    size_t o_deg2   = alloc((size_t)N * 4);
    size_t o_dis2   = alloc((size_t)N * 4);
    size_t o_crow   = alloc((size_t)E * 4);
    size_t o_cw     = alloc((size_t)E * 4);
    size_t o_h      = alloc((size_t)N * 128 * 4);
    size_t o_agg    = alloc((size_t)N * 128 * 4);
    if (ws_size < off) return;   // workspace too small: fail loudly (validation will catch)

    int*   cntOut  = (int*)(ws + o_cntOut);
    int*   cntIn   = (int*)(ws + o_cntIn);
    int*   csr_cur = (int*)(ws + o_cur);
    float* sums    = (float*)(ws + o_sums);
    int*   csr_off = (int*)(ws + o_coff);
    float* dis     = (float*)(ws + o_dis);
    float* deg2    = (float*)(ws + o_deg2);
    float* dis2    = (float*)(ws + o_dis2);
    int*   csr_row = (int*)(ws + o_crow);
    float* csr_w   = (float*)(ws + o_cw);
    float* h       = (float*)(ws + o_h);
    float* agg     = (float*)(ws + o_agg);

    hipMemsetAsync(ws, 0, zbytes, stream);
    k_count<<<(E + 255) / 256, 256, 0, stream>>>(row, col, E, cntOut, cntIn);
    k_scan<<<1, 1024, 0, stream>>>(cntIn, csr_off, N);
    k_nodeinit<<<(N + 255) / 256, 256, 0, stream>>>(cntOut, dis, deg2, N);
    k_edges<<<(E + 255) / 256, 256, 0, stream>>>(row, col, E, dis, deg2, csr_off, csr_cur, csr_row, csr_w);
    k_dis2<<<(N + 255) / 256, 256, 0, stream>>>(deg2, dis2, N);
    k_gemm<<<(N + 31) / 32, 256, 0, stream>>>(x, W, h, N);
    k_agg<<<N, 128, 0, stream>>>(h, csr_off, csr_row, csr_w, dis, dis2, bias, agg, N);
    k_stats<<<256, 256, 0, stream>>>(agg, sums, N);
    k_bnfin<<<1, 128, 0, stream>>>(sums, gamma, beta, N);
    int total4 = N * 32;
    k_final<<<(total4 + 255) / 256, 256, 0, stream>>>(agg, x, sums, out, total4);
}

// Round 2
// 307.457 us; speedup vs baseline: 1.3684x; 1.3684x over previous
//
#include <hip/hip_runtime.h>

constexpr float SLOPE = 0.1f;
constexpr float BN_EPS = 1e-5f;

__device__ inline unsigned bf16rn(float f) {
    unsigned b = __float_as_uint(f);
    return (b + 0x7fffu + ((b >> 16) & 1u)) >> 16;   // RNE to bf16 bits
}

// ---------- K1: degree counting ----------
__global__ void k_count(const int* __restrict__ row, const int* __restrict__ col, int E,
                        int* __restrict__ cntOut, int* __restrict__ cntIn) {
    int i = blockIdx.x * blockDim.x + threadIdx.x;
    if (i < E) {
        atomicAdd(&cntOut[row[i]], 1);
        atomicAdd(&cntIn[col[i]], 1);
    }
}

// ---------- scan phase A: per-block sums of cntIn ----------
__global__ void k_scanA(const int* __restrict__ cntIn, int* __restrict__ part, int N) {
    __shared__ int sm[256];
    int t = threadIdx.x;
    int i = blockIdx.x * 256 + t;
    int v = (i < N) ? cntIn[i] : 0;
    sm[t] = v;
    __syncthreads();
    for (int d = 128; d > 0; d >>= 1) {
        if (t < d) sm[t] += sm[t + d];
        __syncthreads();
    }
    if (t == 0) part[blockIdx.x] = sm[0];
}

// ---------- scan phase B: exclusive scan of partials (nb <= 256) ----------
__global__ void k_scanB(int* __restrict__ part, int nb) {
    __shared__ int sm[256];
    int t = threadIdx.x;
    int v = (t < nb) ? part[t] : 0;
    sm[t] = v;
    __syncthreads();
    for (int d = 1; d < 256; d <<= 1) {
        int u = (t >= d) ? sm[t - d] : 0;
        __syncthreads();
        sm[t] += u;
        __syncthreads();
    }
    if (t < nb) part[t] = sm[t] - v;   // exclusive
}

// ---------- scan phase C: csr_off + fused nodeinit ----------
__global__ void k_scanC(const int* __restrict__ cntIn, const int* __restrict__ part,
                        int* __restrict__ csr_off, const int* __restrict__ cntOut,
                        float* __restrict__ dis, float* __restrict__ deg2, int N) {
    __shared__ int sm[256];
    int t = threadIdx.x;
    int i = blockIdx.x * 256 + t;
    int v = (i < N) ? cntIn[i] : 0;
    sm[t] = v;
    __syncthreads();
    for (int d = 1; d < 256; d <<= 1) {
        int u = (t >= d) ? sm[t - d] : 0;
        __syncthreads();
        sm[t] += u;
        __syncthreads();
    }
    if (i < N) {
        int off = part[blockIdx.x] + sm[t] - v;
        csr_off[i] = off;
        if (i == N - 1) csr_off[N] = off + v;
        float dg = (float)(cntOut[i] + 1);     // deg = outdeg + self-loop
        float ds = rsqrtf(dg);
        dis[i] = ds;
        deg2[i] = 2.0f + ds * ds;              // fill self-loop (2.0) + ei1 self-loop (dis^2)
    }
}

// ---------- K4: per-edge w1, deg2 scatter, packed CSR fill ----------
__global__ void k_edges(const int* __restrict__ row, const int* __restrict__ col, int E,
                        const float* __restrict__ dis, float* __restrict__ deg2,
                        const int* __restrict__ csr_off, int* __restrict__ csr_cur,
                        int2* __restrict__ csr_rw) {
    int i = blockIdx.x * blockDim.x + threadIdx.x;
    if (i < E) {
        int r = row[i], c = col[i];
        float w1 = dis[r] * dis[c];
        atomicAdd(&deg2[c], w1);
        int pos = csr_off[c] + atomicAdd(&csr_cur[c], 1);
        csr_rw[pos] = make_int2(r, __float_as_int(w1));
    }
}

// ---------- K6: h = x @ W^T  (fp32 compute, bf16 output) ----------
// block = 256 threads, 32 rows x 128 cols per block, 4x4 per thread, K tiled by 64
__global__ __launch_bounds__(256) void k_gemm(const float* __restrict__ x,
                                              const float* __restrict__ W,
                                              uint2* __restrict__ h2, int N) {
    __shared__ float wt[64 * 132];   // [k][d], stride 132 breaks bank conflicts
    __shared__ float xs[32 * 128];   // [r][k]
    int tx = threadIdx.x;
    int row0 = blockIdx.x * 32;
    for (int idx = tx; idx < 32 * 128; idx += 256) {
        int r = idx >> 7, k = idx & 127;
        int gr = row0 + r;
        xs[idx] = (gr < N) ? x[(size_t)gr * 128 + k] : 0.0f;
    }
    int c0 = (tx & 31) * 4;
    int r0 = (tx >> 5) * 4;
    float acc[4][4] = {};
    for (int kt = 0; kt < 2; ++kt) {
        __syncthreads();
        for (int idx = tx; idx < 128 * 64; idx += 256) {
            int d = idx >> 6, k = idx & 63;
            wt[k * 132 + d] = W[d * 128 + kt * 64 + k];
        }
        __syncthreads();
        int kbase = kt * 64;
        for (int k = 0; k < 64; ++k) {
            float4 wv = *(const float4*)&wt[k * 132 + c0];
            float xv0 = xs[(r0 + 0) * 128 + kbase + k];
            float xv1 = xs[(r0 + 1) * 128 + kbase + k];
            float xv2 = xs[(r0 + 2) * 128 + kbase + k];
            float xv3 = xs[(r0 + 3) * 128 + kbase + k];
            acc[0][0] += xv0 * wv.x; acc[0][1] += xv0 * wv.y; acc[0][2] += xv0 * wv.z; acc[0][3] += xv0 * wv.w;
            acc[1][0] += xv1 * wv.x; acc[1][1] += xv1 * wv.y; acc[1][2] += xv1 * wv.z; acc[1][3] += xv1 * wv.w;
            acc[2][0] += xv2 * wv.x; acc[2][1] += xv2 * wv.y; acc[2][2] += xv2 * wv.z; acc[2][3] += xv2 * wv.w;
            acc[3][0] += xv3 * wv.x; acc[3][1] += xv3 * wv.y; acc[3][2] += xv3 * wv.z; acc[3][3] += xv3 * wv.w;
        }
    }
    for (int r = 0; r < 4; ++r) {
        int gr = row0 + r0 + r;
        if (gr < N) {
            uint2 o;
            o.x = bf16rn(acc[r][0]) | (bf16rn(acc[r][1]) << 16);
            o.y = bf16rn(acc[r][2]) | (bf16rn(acc[r][3]) << 16);
            h2[(size_t)gr * 32 + (tx & 31)] = o;
        }
    }
}

// ---------- K7: aggregation — wave per node, float4 slots, 2-edge ILP ----------
__global__ __launch_bounds__(256) void k_agg(const uint2* __restrict__ h2,
                                             const int* __restrict__ csr_off,
                                             const int2* __restrict__ csr_rw,
                                             const float* __restrict__ dis,
                                             const float* __restrict__ deg2,
                                             const float* __restrict__ bias,
                                             float4* __restrict__ agg4, int N) {
    int wv = threadIdx.x >> 6;
    int lane = threadIdx.x & 63;
    int ep = lane >> 5;          // 0/1: which half of the edge list
    int slot = lane & 31;        // 4-feature slot
    int j = blockIdx.x * 4 + wv;
    if (j >= N) return;
    float d2j = rsqrtf(deg2[j]);
    float4 acc = make_float4(0.f, 0.f, 0.f, 0.f);
    int s0 = csr_off[j], s1 = csr_off[j + 1];
    for (int s = s0 + ep; s < s1; s += 2) {
        int2 e = csr_rw[s];                               // broadcast 8B
        float w = rsqrtf(deg2[e.x]) * __int_as_float(e.y) * d2j;
        uint2 hv = h2[(size_t)e.x * 32 + slot];           // 8B/lane = 256B/wave-half
        acc.x += w * __uint_as_float(hv.x << 16);
        acc.y += w * __uint_as_float(hv.x & 0xffff0000u);
        acc.z += w * __uint_as_float(hv.y << 16);
        acc.w += w * __uint_as_float(hv.y & 0xffff0000u);
    }
    acc.x += __shfl_xor(acc.x, 32);
    acc.y += __shfl_xor(acc.y, 32);
    acc.z += __shfl_xor(acc.z, 32);
    acc.w += __shfl_xor(acc.w, 32);
    if (ep == 0) {
        float dsj = dis[j];
        float selfw = d2j * d2j * (dsj * dsj + 2.0f);     // both self-loop norms
        uint2 hv = h2[(size_t)j * 32 + slot];
        acc.x += selfw * __uint_as_float(hv.x << 16);
        acc.y += selfw * __uint_as_float(hv.x & 0xffff0000u);
        acc.z += selfw * __uint_as_float(hv.y << 16);
        acc.w += selfw * __uint_as_float(hv.y & 0xffff0000u);
        float4 b = ((const float4*)bias)[slot];
        acc.x += b.x; acc.y += b.y; acc.z += b.z; acc.w += b.w;
        agg4[(size_t)j * 32 + slot] = acc;
    }
}

// ---------- K8: BN batch stats (sum, sumsq per feature) ----------
__global__ void k_stats(const float* __restrict__ agg, float* __restrict__ sums, int N) {
    int d = threadIdx.x & 127;
    int stream_id = blockIdx.x * 2 + (threadIdx.x >> 7);
    int nstreams = gridDim.x * 2;
    float s = 0.0f, sq = 0.0f;
    for (int i = stream_id; i < N; i += nstreams) {
        float v = agg[(size_t)i * 128 + d];
        s += v; sq += v * v;
    }
    atomicAdd(&sums[d], s);
    atomicAdd(&sums[128 + d], sq);
}

// ---------- K9: fold BN into scale/shift ----------
__global__ void k_bnfin(float* __restrict__ sums, const float* __restrict__ gamma,
                        const float* __restrict__ beta, int N) {
    int d = threadIdx.x;
    float invN = 1.0f / (float)N;
    float mu = sums[d] * invN;
    float var = sums[128 + d] * invN - mu * mu;   // biased var, like jnp.var
    float sc = gamma[d] * rsqrtf(var + BN_EPS);
    sums[256 + d] = sc;
    sums[384 + d] = beta[d] - mu * sc;
}

// ---------- K10: BN-apply + LeakyReLU + residual + LeakyReLU ----------
__global__ void k_final(const float* __restrict__ agg, const float* __restrict__ x,
                        const float* __restrict__ sums, float* __restrict__ out, int total4) {
    int idx = blockIdx.x * blockDim.x + threadIdx.x;
    if (idx >= total4) return;
    int c4 = (idx & 31) * 4;
    float4 a = *(const float4*)&agg[(size_t)idx * 4];
    float4 xv = *(const float4*)&x[(size_t)idx * 4];
    float ap[4] = {a.x, a.y, a.z, a.w};
    float xp[4] = {xv.x, xv.y, xv.z, xv.w};
    float op[4];
#pragma unroll
    for (int j = 0; j < 4; ++j) {
        int d = c4 + j;
        float bn = ap[j] * sums[256 + d] + sums[384 + d];
        float act = bn > 0.0f ? bn : SLOPE * bn;
        float v = act + xp[j];
        op[j] = v > 0.0f ? v : SLOPE * v;
    }
    *(float4*)&out[(size_t)idx * 4] = make_float4(op[0], op[1], op[2], op[3]);
}

extern "C" void kernel_launch(void* const* d_in, const int* in_sizes, int n_in,
                              void* d_out, int out_size, void* d_ws, size_t ws_size,
                              hipStream_t stream) {
    const float* x     = (const float*)d_in[0];
    const float* W     = (const float*)d_in[1];
    const float* bias  = (const float*)d_in[2];
    const float* gamma = (const float*)d_in[3];
    const float* beta  = (const float*)d_in[4];
    const int*   ei    = (const int*)d_in[5];
    int N = in_sizes[0] / 128;
    int E = in_sizes[5] / 2;
    const int* row = ei;
    const int* col = ei + E;
    float* out = (float*)d_out;

    char* ws = (char*)d_ws;
    size_t off = 0;
    auto alloc = [&](size_t b) { size_t o = off; off = (off + b + 255) & ~(size_t)255; return o; };
    size_t o_cntOut = alloc((size_t)N * 4);
    size_t o_cntIn  = alloc((size_t)N * 4);
    size_t o_cur    = alloc((size_t)N * 4);
    size_t o_sums   = alloc(512 * 4);
    size_t zbytes   = off;                       // zeroed region
    size_t o_coff   = alloc((size_t)(N + 1) * 4);
    size_t o_part   = alloc(256 * 4);
    size_t o_dis    = alloc((size_t)N * 4);
    size_t o_deg2   = alloc((size_t)N * 4);
    size_t o_crw    = alloc((size_t)E * 8);
    size_t o_h      = alloc((size_t)N * 128 * 2);   // bf16 h
    size_t o_agg    = alloc((size_t)N * 128 * 4);
    if (ws_size < off) return;

    int*   cntOut  = (int*)(ws + o_cntOut);
    int*   cntIn   = (int*)(ws + o_cntIn);
    int*   csr_cur = (int*)(ws + o_cur);
    float* sums    = (float*)(ws + o_sums);
    int*   csr_off = (int*)(ws + o_coff);
    int*   part    = (int*)(ws + o_part);
    float* dis     = (float*)(ws + o_dis);
    float* deg2    = (float*)(ws + o_deg2);
    int2*  csr_rw  = (int2*)(ws + o_crw);
    uint2* h2      = (uint2*)(ws + o_h);
    float* agg     = (float*)(ws + o_agg);

    int nb = (N + 255) / 256;   // scan blocks (196 <= 256)

    hipMemsetAsync(ws, 0, zbytes, stream);
    k_count<<<(E + 255) / 256, 256, 0, stream>>>(row, col, E, cntOut, cntIn);
    k_scanA<<<nb, 256, 0, stream>>>(cntIn, part, N);
    k_scanB<<<1, 256, 0, stream>>>(part, nb);
    k_scanC<<<nb, 256, 0, stream>>>(cntIn, part, csr_off, cntOut, dis, deg2, N);
    k_edges<<<(E + 255) / 256, 256, 0, stream>>>(row, col, E, dis, deg2, csr_off, csr_cur, csr_rw);
    k_gemm<<<(N + 31) / 32, 256, 0, stream>>>(x, W, h2, N);
    k_agg<<<(N + 3) / 4, 256, 0, stream>>>(h2, csr_off, csr_rw, dis, deg2, bias, (float4*)agg, N);
    k_stats<<<256, 256, 0, stream>>>(agg, sums, N);
    k_bnfin<<<1, 128, 0, stream>>>(sums, gamma, beta, N);
    int total4 = N * 32;
    k_final<<<(total4 + 255) / 256, 256, 0, stream>>>(agg, x, sums, out, total4);
}

// Round 3
// 294.288 us; speedup vs baseline: 1.4296x; 1.0448x over previous
//
#include <hip/hip_runtime.h>

constexpr float SLOPE = 0.1f;
constexpr float BN_EPS = 1e-5f;

typedef __attribute__((ext_vector_type(8))) short bf16x8;
typedef __attribute__((ext_vector_type(4))) float f32x4;

__device__ inline unsigned bf16rn(float f) {
    unsigned b = __float_as_uint(f);
    return (b + 0x7fffu + ((b >> 16) & 1u)) >> 16;   // RNE to bf16 bits
}

// ---------- K1: degree counting ----------
__global__ void k_count(const int* __restrict__ row, const int* __restrict__ col, int E,
                        int* __restrict__ cntOut, int* __restrict__ cntIn) {
    int i = blockIdx.x * blockDim.x + threadIdx.x;
    if (i < E) {
        atomicAdd(&cntOut[row[i]], 1);
        atomicAdd(&cntIn[col[i]], 1);
    }
}

// ---------- scan phase A: per-block sums of cntIn ----------
__global__ void k_scanA(const int* __restrict__ cntIn, int* __restrict__ part, int N) {
    __shared__ int sm[256];
    int t = threadIdx.x;
    int i = blockIdx.x * 256 + t;
    int v = (i < N) ? cntIn[i] : 0;
    sm[t] = v;
    __syncthreads();
    for (int d = 128; d > 0; d >>= 1) {
        if (t < d) sm[t] += sm[t + d];
        __syncthreads();
    }
    if (t == 0) part[blockIdx.x] = sm[0];
}

// ---------- scan phase B: exclusive scan of partials (nb <= 256) ----------
__global__ void k_scanB(int* __restrict__ part, int nb) {
    __shared__ int sm[256];
    int t = threadIdx.x;
    int v = (t < nb) ? part[t] : 0;
    sm[t] = v;
    __syncthreads();
    for (int d = 1; d < 256; d <<= 1) {
        int u = (t >= d) ? sm[t - d] : 0;
        __syncthreads();
        sm[t] += u;
        __syncthreads();
    }
    if (t < nb) part[t] = sm[t] - v;   // exclusive
}

// ---------- scan phase C: csr_off + fused nodeinit ----------
__global__ void k_scanC(const int* __restrict__ cntIn, const int* __restrict__ part,
                        int* __restrict__ csr_off, const int* __restrict__ cntOut,
                        float* __restrict__ dis, float* __restrict__ deg2, int N) {
    __shared__ int sm[256];
    int t = threadIdx.x;
    int i = blockIdx.x * 256 + t;
    int v = (i < N) ? cntIn[i] : 0;
    sm[t] = v;
    __syncthreads();
    for (int d = 1; d < 256; d <<= 1) {
        int u = (t >= d) ? sm[t - d] : 0;
        __syncthreads();
        sm[t] += u;
        __syncthreads();
    }
    if (i < N) {
        int off = part[blockIdx.x] + sm[t] - v;
        csr_off[i] = off;
        if (i == N - 1) csr_off[N] = off + v;
        float dg = (float)(cntOut[i] + 1);     // deg = outdeg + self-loop
        float ds = rsqrtf(dg);
        dis[i] = ds;
        deg2[i] = 2.0f + ds * ds;              // fill self-loop (2.0) + ei1 self-loop (dis^2)
    }
}

// ---------- K4: per-edge w1 -> deg2 atomic, 4B CSR scatter ----------
__global__ void k_edges(const int* __restrict__ row, const int* __restrict__ col, int E,
                        const float* __restrict__ dis, float* __restrict__ deg2,
                        const int* __restrict__ csr_off, int* __restrict__ csr_cur,
                        int* __restrict__ csr_row) {
    int i = blockIdx.x * blockDim.x + threadIdx.x;
    if (i < E) {
        int r = row[i], c = col[i];
        float w1 = dis[r] * dis[c];
        atomicAdd(&deg2[c], w1);
        int pos = csr_off[c] + atomicAdd(&csr_cur[c], 1);
        csr_row[pos] = r;
    }
}

// ---------- K5: per-node weight factors ----------
// edge norm(r->j) = dw[r]*dw[j];  self-loop total = selfw[j]
__global__ void k_node2(const float* __restrict__ deg2, const float* __restrict__ dis,
                        float* __restrict__ dw, float* __restrict__ selfw, int N) {
    int i = blockIdx.x * blockDim.x + threadIdx.x;
    if (i < N) {
        float d2 = rsqrtf(deg2[i]);
        float ds = dis[i];
        dw[i] = ds * d2;
        selfw[i] = d2 * d2 * (ds * ds + 2.0f);
    }
}

// ---------- K6: h = x @ W^T via bf16 MFMA (x split hi/lo for fp32-class accuracy) ----------
// block 256 = 4 waves; wave computes 16 rows x 128 cols; K=128 in 4 steps of 32
__global__ __launch_bounds__(256) void k_gemm(const float* __restrict__ x,
                                              const float* __restrict__ W,
                                              unsigned* __restrict__ h32, int N) {
    __shared__ unsigned short wb[128 * 136];   // bf16 W[d][k], k-stride 136 (pad breaks conflicts)
    int tx = threadIdx.x;
    for (int idx = tx; idx < 128 * 64; idx += 256) {
        int d = idx >> 6;
        int kp = (idx & 63) * 2;
        float2 wv = *(const float2*)&W[d * 128 + kp];
        wb[d * 136 + kp]     = (unsigned short)bf16rn(wv.x);
        wb[d * 136 + kp + 1] = (unsigned short)bf16rn(wv.y);
    }
    __syncthreads();
    int wave = tx >> 6, l = tx & 63;
    int lr = l & 15, kg = l >> 4;
    int row = blockIdx.x * 64 + wave * 16 + lr;
    int rclamp = min(row, N - 1);
    f32x4 acc[8];
#pragma unroll
    for (int ct = 0; ct < 8; ++ct) acc[ct] = (f32x4){0.f, 0.f, 0.f, 0.f};
#pragma unroll
    for (int kt = 0; kt < 4; ++kt) {
        int k0 = kt * 32 + kg * 8;
        float xv[8];
        *(float4*)&xv[0] = *(const float4*)&x[(size_t)rclamp * 128 + k0];
        *(float4*)&xv[4] = *(const float4*)&x[(size_t)rclamp * 128 + k0 + 4];
        bf16x8 ahi, alo;
#pragma unroll
        for (int j = 0; j < 8; ++j) {
            unsigned hb = bf16rn(xv[j]);
            ahi[j] = (short)hb;
            alo[j] = (short)bf16rn(xv[j] - __uint_as_float(hb << 16));
        }
#pragma unroll
        for (int ct = 0; ct < 8; ++ct) {
            bf16x8 b = *(const bf16x8*)&wb[(ct * 16 + lr) * 136 + k0];
            acc[ct] = __builtin_amdgcn_mfma_f32_16x16x32_bf16(ahi, b, acc[ct], 0, 0, 0);
            acc[ct] = __builtin_amdgcn_mfma_f32_16x16x32_bf16(alo, b, acc[ct], 0, 0, 0);
        }
    }
    // C/D: row = kg*4+reg, col = ct*16+lr  (m89-verified). Pack bf16 d-pairs across lane pairs.
    int rowbase = blockIdx.x * 64 + wave * 16 + kg * 4;
#pragma unroll
    for (int ct = 0; ct < 8; ++ct) {
#pragma unroll
        for (int reg = 0; reg < 4; ++reg) {
            float v = acc[ct][reg];
            float pv = __shfl_xor(v, 1);
            int orow = rowbase + reg;
            if ((l & 1) == 0 && orow < N) {
                unsigned pk = bf16rn(v) | (bf16rn(pv) << 16);
                h32[(size_t)orow * 64 + ct * 8 + (lr >> 1)] = pk;
            }
        }
    }
}

// ---------- K7: aggregation — wave per node, 2-edge ILP, factorized weights ----------
__global__ __launch_bounds__(256) void k_agg(const uint2* __restrict__ h2,
                                             const int* __restrict__ csr_off,
                                             const int* __restrict__ csr_row,
                                             const float* __restrict__ dw,
                                             const float* __restrict__ selfw,
                                             const float* __restrict__ bias,
                                             float4* __restrict__ agg4, int N) {
    int wv = threadIdx.x >> 6;
    int lane = threadIdx.x & 63;
    int ep = lane >> 5;          // 0/1: which half of the edge list
    int slot = lane & 31;        // 4-feature slot
    int j = blockIdx.x * 4 + wv;
    if (j >= N) return;
    float dwj = dw[j];
    float4 acc = make_float4(0.f, 0.f, 0.f, 0.f);
    int s0 = csr_off[j], s1 = csr_off[j + 1];
    for (int s = s0 + ep; s < s1; s += 2) {
        int r = csr_row[s];                               // broadcast 4B
        float w = dw[r] * dwj;                            // broadcast 4B, L2-resident table
        uint2 hv = h2[(size_t)r * 32 + slot];             // 8B/lane = 256B/half-wave
        acc.x += w * __uint_as_float(hv.x << 16);
        acc.y += w * __uint_as_float(hv.x & 0xffff0000u);
        acc.z += w * __uint_as_float(hv.y << 16);
        acc.w += w * __uint_as_float(hv.y & 0xffff0000u);
    }
    acc.x += __shfl_xor(acc.x, 32);
    acc.y += __shfl_xor(acc.y, 32);
    acc.z += __shfl_xor(acc.z, 32);
    acc.w += __shfl_xor(acc.w, 32);
    if (ep == 0) {
        float sw = selfw[j];
        uint2 hv = h2[(size_t)j * 32 + slot];
        acc.x += sw * __uint_as_float(hv.x << 16);
        acc.y += sw * __uint_as_float(hv.x & 0xffff0000u);
        acc.z += sw * __uint_as_float(hv.y << 16);
        acc.w += sw * __uint_as_float(hv.y & 0xffff0000u);
        float4 b = ((const float4*)bias)[slot];
        acc.x += b.x; acc.y += b.y; acc.z += b.z; acc.w += b.w;
        agg4[(size_t)j * 32 + slot] = acc;
    }
}

// ---------- K8: BN batch stats (sum, sumsq per feature) ----------
__global__ void k_stats(const float* __restrict__ agg, float* __restrict__ sums, int N) {
    int d = threadIdx.x & 127;
    int stream_id = blockIdx.x * 2 + (threadIdx.x >> 7);
    int nstreams = gridDim.x * 2;
    float s = 0.0f, sq = 0.0f;
    for (int i = stream_id; i < N; i += nstreams) {
        float v = agg[(size_t)i * 128 + d];
        s += v; sq += v * v;
    }
    atomicAdd(&sums[d], s);
    atomicAdd(&sums[128 + d], sq);
}

// ---------- K9: fold BN into scale/shift ----------
__global__ void k_bnfin(float* __restrict__ sums, const float* __restrict__ gamma,
                        const float* __restrict__ beta, int N) {
    int d = threadIdx.x;
    float invN = 1.0f / (float)N;
    float mu = sums[d] * invN;
    float var = sums[128 + d] * invN - mu * mu;   // biased var, like jnp.var
    float sc = gamma[d] * rsqrtf(var + BN_EPS);
    sums[256 + d] = sc;
    sums[384 + d] = beta[d] - mu * sc;
}

// ---------- K10: BN-apply + LeakyReLU + residual + LeakyReLU ----------
__global__ void k_final(const float* __restrict__ agg, const float* __restrict__ x,
                        const float* __restrict__ sums, float* __restrict__ out, int total4) {
    int idx = blockIdx.x * blockDim.x + threadIdx.x;
    if (idx >= total4) return;
    int c4 = (idx & 31) * 4;
    float4 a = *(const float4*)&agg[(size_t)idx * 4];
    float4 xv = *(const float4*)&x[(size_t)idx * 4];
    float ap[4] = {a.x, a.y, a.z, a.w};
    float xp[4] = {xv.x, xv.y, xv.z, xv.w};
    float op[4];
#pragma unroll
    for (int j = 0; j < 4; ++j) {
        int d = c4 + j;
        float bn = ap[j] * sums[256 + d] + sums[384 + d];
        float act = bn > 0.0f ? bn : SLOPE * bn;
        float v = act + xp[j];
        op[j] = v > 0.0f ? v : SLOPE * v;
    }
    *(float4*)&out[(size_t)idx * 4] = make_float4(op[0], op[1], op[2], op[3]);
}

extern "C" void kernel_launch(void* const* d_in, const int* in_sizes, int n_in,
                              void* d_out, int out_size, void* d_ws, size_t ws_size,
                              hipStream_t stream) {
    const float* x     = (const float*)d_in[0];
    const float* W     = (const float*)d_in[1];
    const float* bias  = (const float*)d_in[2];
    const float* gamma = (const float*)d_in[3];
    const float* beta  = (const float*)d_in[4];
    const int*   ei    = (const int*)d_in[5];
    int N = in_sizes[0] / 128;
    int E = in_sizes[5] / 2;
    const int* row = ei;
    const int* col = ei + E;
    float* out = (float*)d_out;

    char* ws = (char*)d_ws;
    size_t off = 0;
    auto alloc = [&](size_t b) { size_t o = off; off = (off + b + 255) & ~(size_t)255; return o; };
    size_t o_cntOut = alloc((size_t)N * 4);
    size_t o_cntIn  = alloc((size_t)N * 4);
    size_t o_cur    = alloc((size_t)N * 4);
    size_t o_sums   = alloc(512 * 4);
    size_t zbytes   = off;                       // zeroed region
    size_t o_coff   = alloc((size_t)(N + 1) * 4);
    size_t o_part   = alloc(256 * 4);
    size_t o_dis    = alloc((size_t)N * 4);
    size_t o_deg2   = alloc((size_t)N * 4);
    size_t o_dw     = alloc((size_t)N * 4);
    size_t o_selfw  = alloc((size_t)N * 4);
    size_t o_crow   = alloc((size_t)E * 4);
    size_t o_h      = alloc((size_t)N * 128 * 2);   // bf16 h
    size_t o_agg    = alloc((size_t)N * 128 * 4);
    if (ws_size < off) return;

    int*   cntOut  = (int*)(ws + o_cntOut);
    int*   cntIn   = (int*)(ws + o_cntIn);
    int*   csr_cur = (int*)(ws + o_cur);
    float* sums    = (float*)(ws + o_sums);
    int*   csr_off = (int*)(ws + o_coff);
    int*   part    = (int*)(ws + o_part);
    float* dis     = (float*)(ws + o_dis);
    float* deg2    = (float*)(ws + o_deg2);
    float* dw      = (float*)(ws + o_dw);
    float* selfw   = (float*)(ws + o_selfw);
    int*   csr_row = (int*)(ws + o_crow);
    unsigned* h32  = (unsigned*)(ws + o_h);
    float* agg     = (float*)(ws + o_agg);

    int nb = (N + 255) / 256;

    hipMemsetAsync(ws, 0, zbytes, stream);
    k_count<<<(E + 255) / 256, 256, 0, stream>>>(row, col, E, cntOut, cntIn);
    k_scanA<<<nb, 256, 0, stream>>>(cntIn, part, N);
    k_scanB<<<1, 256, 0, stream>>>(part, nb);
    k_scanC<<<nb, 256, 0, stream>>>(cntIn, part, csr_off, cntOut, dis, deg2, N);
    k_edges<<<(E + 255) / 256, 256, 0, stream>>>(row, col, E, dis, deg2, csr_off, csr_cur, csr_row);
    k_node2<<<(N + 255) / 256, 256, 0, stream>>>(deg2, dis, dw, selfw, N);
    k_gemm<<<(N + 63) / 64, 256, 0, stream>>>(x, W, h32, N);
    k_agg<<<(N + 3) / 4, 256, 0, stream>>>((const uint2*)h32, csr_off, csr_row, dw, selfw, bias, (float4*)agg, N);
    k_stats<<<256, 256, 0, stream>>>(agg, sums, N);
    k_bnfin<<<1, 128, 0, stream>>>(sums, gamma, beta, N);
    int total4 = N * 32;
    k_final<<<(total4 + 255) / 256, 256, 0, stream>>>(agg, x, sums, out, total4);
}